// Round 1
// baseline (146.182 us; speedup 1.0000x reference)
//
#include <hip/hip_runtime.h>
#include <math.h>

// Problem constants (fixed by reference setup_inputs):
//   inputs:         (B=64, N=1024, C=192) fp32
//   groups_range1:  (G=4,) fp32
//   alpha_activ:    (G=4, C=192) fp32
// Outputs: (ori_activ, activ), each (B,N,C) fp32, concatenated in d_out.
#define GG 4
#define CC 192
#define TOTAL_ELEMS (64 * 1024 * 192)   // 12,582,912
#define TOTAL_VEC   (TOTAL_ELEMS / 4)   // 3,145,728 float4s

// block=192 (3 waves), grid=2048 -> T = 393,216 threads.
// 4*T % 192 == 0, so each thread's c-quadruple is invariant across the
// grid-stride loop -> softmax weights live in registers, loaded once.
// TOTAL_VEC / T = 8 iterations exactly (no tail).
#define BLOCK 192
#define GRID  2048

__global__ __launch_bounds__(BLOCK) void qmodule_kernel(
    const float* __restrict__ x,
    const float* __restrict__ range1,
    const float* __restrict__ alpha,
    float* __restrict__ out_ori,
    float* __restrict__ out_q)
{
    const int tid = blockIdx.x * BLOCK + threadIdx.x;
    const int T   = GRID * BLOCK;
    const int c0  = (4 * tid) % CC;   // fixed channel base for this thread

    // Per-group quantization params (uniform across threads; ~12 regs).
    float rg[GG], invb[GG], bq[GG];
#pragma unroll
    for (int g = 0; g < GG; ++g) {
        float r = range1[g];
        rg[g] = r;
        float b = r / 255.0f;          // levels = 2^8 - 1
        if (b == 0.0f) {               // ref: zero_mask -> q = 0
            invb[g] = 0.0f;
            bq[g]   = 0.0f;
        } else {
            invb[g] = 1.0f / b;
            bq[g]   = b;
        }
    }

    // Softmax over g for this thread's 4 channels (computed once; 16 regs).
    float w[4][GG];
#pragma unroll
    for (int j = 0; j < 4; ++j) {
        const int c = c0 + j;
        float a0 = alpha[0 * CC + c];
        float a1 = alpha[1 * CC + c];
        float a2 = alpha[2 * CC + c];
        float a3 = alpha[3 * CC + c];
        float m  = fmaxf(fmaxf(a0, a1), fmaxf(a2, a3));
        float e0 = expf(a0 - m);
        float e1 = expf(a1 - m);
        float e2 = expf(a2 - m);
        float e3 = expf(a3 - m);
        float s  = 1.0f / (e0 + e1 + e2 + e3);
        w[j][0] = e0 * s;
        w[j][1] = e1 * s;
        w[j][2] = e2 * s;
        w[j][3] = e3 * s;
    }

    const float4* __restrict__ xv4 = reinterpret_cast<const float4*>(x);
    float4* __restrict__ ov4 = reinterpret_cast<float4*>(out_ori);
    float4* __restrict__ qv4 = reinterpret_cast<float4*>(out_q);

    for (int f = tid; f < TOTAL_VEC; f += T) {
        const float4 xv = xv4[f];
        float xs[4] = {xv.x, xv.y, xv.z, xv.w};
        float oa[4] = {0.0f, 0.0f, 0.0f, 0.0f};
        float qa[4] = {0.0f, 0.0f, 0.0f, 0.0f};

#pragma unroll
        for (int g = 0; g < GG; ++g) {
            const float r  = rg[g];
            const float ib = invb[g];
            const float bb = bq[g];
#pragma unroll
            for (int j = 0; j < 4; ++j) {
                const float xx  = xs[j];
                // ori = 0.5*(|x| - |x - r| + r); exactly the reference formula.
                // When r == 0 this is exactly 0 (matches zero_mask on ori).
                const float ori = 0.5f * (fabsf(xx) - fabsf(xx - r) + r);
                // q = rint(ori / b) * b; rintf = round-half-even (jnp.round).
                const float q   = rintf(ori * ib) * bb;
                const float wt  = w[j][g];
                oa[j] = fmaf(ori, wt, oa[j]);
                qa[j] = fmaf(q,   wt, qa[j]);
            }
        }

        float4 ov = {oa[0], oa[1], oa[2], oa[3]};
        float4 qv = {qa[0], qa[1], qa[2], qa[3]};
        ov4[f] = ov;
        qv4[f] = qv;
    }
}

extern "C" void kernel_launch(void* const* d_in, const int* in_sizes, int n_in,
                              void* d_out, int out_size, void* d_ws, size_t ws_size,
                              hipStream_t stream)
{
    const float* x      = (const float*)d_in[0];  // inputs (B,N,C)
    const float* range1 = (const float*)d_in[1];  // groups_range1 (G,)
    const float* alpha  = (const float*)d_in[2];  // alpha_activ (G,C)

    float* out     = (float*)d_out;
    float* out_ori = out;                 // ori_activ first (return order)
    float* out_q   = out + TOTAL_ELEMS;   // activ second

    qmodule_kernel<<<GRID, BLOCK, 0, stream>>>(x, range1, alpha, out_ori, out_q);
}

// Round 3
// 144.436 us; speedup vs baseline: 1.0121x; 1.0121x over previous
//
#include <hip/hip_runtime.h>
#include <math.h>

// Problem constants (fixed by reference setup_inputs):
//   inputs:         (B=64, N=1024, C=192) fp32
//   groups_range1:  (G=4,) fp32
//   alpha_activ:    (G=4, C=192) fp32
// Outputs: (ori_activ, activ), each (B,N,C) fp32, concatenated in d_out.
#define GG 4
#define CC 192
#define TOTAL_ELEMS (64 * 1024 * 192)   // 12,582,912
#define TOTAL_VEC   (TOTAL_ELEMS / 4)   // 3,145,728 float4s

// block=192 (3 waves), grid=2048 -> T = 393,216 threads.
// 4*T % 192 == 0, so each thread's c-quadruple is invariant across the
// grid-stride loop -> softmax weights live in registers, loaded once.
// TOTAL_VEC / T = 8 iterations exactly (no tail).
#define BLOCK 192
#define GRID  2048

// Native clang vector type: required by __builtin_nontemporal_load/store
// (HIP's float4 is a struct and is rejected by the builtin).
typedef float v4f __attribute__((ext_vector_type(4)));

__global__ __launch_bounds__(BLOCK) void qmodule_kernel(
    const float* __restrict__ x,
    const float* __restrict__ range1,
    const float* __restrict__ alpha,
    float* __restrict__ out_ori,
    float* __restrict__ out_q)
{
    const int tid = blockIdx.x * BLOCK + threadIdx.x;
    const int T   = GRID * BLOCK;
    const int c0  = (4 * tid) % CC;   // fixed channel base for this thread

    // Per-group quantization params (uniform across threads; ~12 regs).
    float rg[GG], invb[GG], bq[GG];
#pragma unroll
    for (int g = 0; g < GG; ++g) {
        float r = range1[g];
        rg[g] = r;
        float b = r / 255.0f;          // levels = 2^8 - 1
        if (b == 0.0f) {               // ref: zero_mask -> q = 0
            invb[g] = 0.0f;
            bq[g]   = 0.0f;
        } else {
            invb[g] = 1.0f / b;
            bq[g]   = b;
        }
    }

    // Softmax over g for this thread's 4 channels (computed once; 16 regs).
    // __expf: hw exp2-based fast path; softmax weight error ~1e-6, far under
    // the 6.5e-3 output threshold (R1 margin was 6.7x with exact expf).
    float w[4][GG];
#pragma unroll
    for (int j = 0; j < 4; ++j) {
        const int c = c0 + j;
        float a0 = alpha[0 * CC + c];
        float a1 = alpha[1 * CC + c];
        float a2 = alpha[2 * CC + c];
        float a3 = alpha[3 * CC + c];
        float m  = fmaxf(fmaxf(a0, a1), fmaxf(a2, a3));
        float e0 = __expf(a0 - m);
        float e1 = __expf(a1 - m);
        float e2 = __expf(a2 - m);
        float e3 = __expf(a3 - m);
        float s  = 1.0f / (e0 + e1 + e2 + e3);
        w[j][0] = e0 * s;
        w[j][1] = e1 * s;
        w[j][2] = e2 * s;
        w[j][3] = e3 * s;
    }

    const v4f* __restrict__ xv4 = reinterpret_cast<const v4f*>(x);
    v4f* __restrict__ ov4 = reinterpret_cast<v4f*>(out_ori);
    v4f* __restrict__ qv4 = reinterpret_cast<v4f*>(out_q);

    for (int f = tid; f < TOTAL_VEC; f += T) {
        // x is read exactly once; outputs never re-read -> nontemporal hints
        // keep the 151 MB stream out of L2's way.
        const v4f xv = __builtin_nontemporal_load(&xv4[f]);
        float xs[4] = {xv.x, xv.y, xv.z, xv.w};
        float oa[4] = {0.0f, 0.0f, 0.0f, 0.0f};
        float qa[4] = {0.0f, 0.0f, 0.0f, 0.0f};

#pragma unroll
        for (int g = 0; g < GG; ++g) {
            const float r  = rg[g];
            const float ib = invb[g];
            const float bb = bq[g];
#pragma unroll
            for (int j = 0; j < 4; ++j) {
                const float xx  = xs[j];
                // ori = 0.5*(|x| - |x - r| + r); exactly the reference formula.
                // When r == 0 this is exactly 0 (matches zero_mask on ori).
                const float ori = 0.5f * (fabsf(xx) - fabsf(xx - r) + r);
                // q = rint(ori / b) * b; rintf = round-half-even (jnp.round).
                const float q   = rintf(ori * ib) * bb;
                const float wt  = w[j][g];
                oa[j] = fmaf(ori, wt, oa[j]);
                qa[j] = fmaf(q,   wt, qa[j]);
            }
        }

        v4f ov = {oa[0], oa[1], oa[2], oa[3]};
        v4f qv = {qa[0], qa[1], qa[2], qa[3]};
        __builtin_nontemporal_store(ov, &ov4[f]);
        __builtin_nontemporal_store(qv, &qv4[f]);
    }
}

extern "C" void kernel_launch(void* const* d_in, const int* in_sizes, int n_in,
                              void* d_out, int out_size, void* d_ws, size_t ws_size,
                              hipStream_t stream)
{
    const float* x      = (const float*)d_in[0];  // inputs (B,N,C)
    const float* range1 = (const float*)d_in[1];  // groups_range1 (G,)
    const float* alpha  = (const float*)d_in[2];  // alpha_activ (G,C)

    float* out     = (float*)d_out;
    float* out_ori = out;                 // ori_activ first (return order)
    float* out_q   = out + TOTAL_ELEMS;   // activ second

    qmodule_kernel<<<GRID, BLOCK, 0, stream>>>(x, range1, alpha, out_ori, out_q);
}